// Round 4
// baseline (1367.054 us; speedup 1.0000x reference)
//
#include <hip/hip_runtime.h>
#include <math.h>

#define PW 160
#define PSQ 25600          // 160*160
#define NB 4
#define NX 307200          // NB*3*PSQ
#define NDIM 76800         // 3*PSQ

typedef __attribute__((ext_vector_type(8))) short short8;
typedef __attribute__((ext_vector_type(4))) float float4v;

struct TS40 { float t[40]; };
struct MC40 { float m[40]; float A; };

__device__ __forceinline__ unsigned short bf16s(float f) {   // RNE (one-time repacks only)
    unsigned u = __builtin_bit_cast(unsigned, f);
    return (unsigned short)((u + 0x7FFFu + ((u >> 16) & 1u)) >> 16);
}
// pack 2 f32 -> bf16x2 (truncating) in ONE v_perm_b32: hi goes to high half
__device__ __forceinline__ unsigned pk2(float hi, float lo) {
    return __builtin_amdgcn_perm(__builtin_bit_cast(unsigned, hi),
                                 __builtin_bit_cast(unsigned, lo), 0x07060302u);
}

// ---------------- time embedding
__global__ void emb_kernel(const float* __restrict__ wt, const float* __restrict__ bt,
                           float* __restrict__ emb, TS40 ts) {
    int r = blockIdx.x, k = threadIdx.x;   // 64 threads
    __shared__ float e64[64];
    float t = ts.t[r];
    int j = k & 31;
    float freq = expf(-0.29710775393471556f * (float)j);  // -ln(10000)/31
    float a = t * 999.0f * freq;
    e64[k] = (k < 32) ? sinf(a) : cosf(a);
    __syncthreads();
    if (k < 32) {
        float acc = bt[k];
        #pragma unroll 8
        for (int q = 0; q < 64; q++) acc += e64[q] * wt[q * 32 + k];
        emb[r * 32 + k] = acc;
    }
}

// ---------------- repack weights into MFMA A-fragment order (bf16, RNE)
__global__ void repack_kernel(const float* __restrict__ w1, const float* __restrict__ w2,
                              const float* __restrict__ w3, short* __restrict__ w1p,
                              short* __restrict__ w2p, short* __restrict__ w3p) {
    int tid = blockIdx.x * 256 + threadIdx.x;
    if (tid < 9216) {
        int j = tid & 7, co = (tid >> 3) & 31, q4 = tid >> 8;
        int tap = q4 >> 2, quad = q4 & 3, ci = quad * 8 + j;
        w2p[tid] = (short)bf16s(w2[(co * 32 + ci) * 9 + tap]);
    }
    if (tid < 4608) {
        int j = tid & 7, co = (tid >> 3) & 15, q4 = tid >> 7;
        int tap = q4 >> 2, quad = q4 & 3, ci = quad * 8 + j;
        float v = (co < 3) ? w3[(co * 32 + ci) * 9 + tap] : 0.0f;
        w3p[tid] = (short)bf16s(v);
    }
    if (tid < 1024) {
        int j = tid & 7, co = (tid >> 3) & 31, quad = tid >> 8;
        int k = quad * 8 + j;
        float v = 0.0f;
        if (k < 27) { int tap = k / 3; int ci = k - tap * 3; v = w1[(co * 3 + ci) * 9 + tap]; }
        w1p[tid] = (short)bf16s(v);
    }
}

// ---------------- teps = raw conv1(eps), full image, bf16 [pix][32]
__global__ __launch_bounds__(256) void teps_conv1(
    const float* __restrict__ xin, const short* __restrict__ w1p,
    short* __restrict__ outH) {
    const int tile = blockIdx.x;
    const int ty0 = (tile / 10) * 16, tx0 = (tile % 10) * 16;
    const int tid = threadIdx.x;
    const int lane = tid & 63, wv = tid >> 6;
    const int n = lane & 15, quad = lane >> 4;
    __shared__ float sX[3 * 324];
    for (int idx = tid; idx < 3 * 324; idx += 256) {
        int ci = idx / 324, p = idx - ci * 324;
        int ly = p / 18, lx = p - ly * 18;
        int gy = ty0 + ly - 1, gx = tx0 + lx - 1;
        float v = 0.0f;
        if ((unsigned)gy < 160u && (unsigned)gx < 160u)
            v = xin[(size_t)ci * PSQ + gy * PW + gx];
        sX[idx] = v;
    }
    __syncthreads();
    int offj[8], valj[8];
    #pragma unroll
    for (int j = 0; j < 8; ++j) {
        int k = quad * 8 + j;
        valj[j] = (k < 27);
        int tap = k / 3, ci = k - tap * 3;
        int dy = tap / 3, dx = tap - dy * 3;
        offj[j] = valj[j] ? (ci * 324 + dy * 18 + dx + n) : 0;
    }
    short8 a0 = *(const short8*)&w1p[(quad * 32 + n) * 8];
    short8 a1 = *(const short8*)&w1p[(quad * 32 + 16 + n) * 8];
    #pragma unroll
    for (int r = 0; r < 4; ++r) {
        int row = wv * 4 + r;
        short8 bb;
        #pragma unroll
        for (int j = 0; j < 8; ++j) {
            float v = valj[j] ? sX[offj[j] + row * 18] : 0.0f;
            bb[j] = (short)bf16s(v);
        }
        float4v acc0 = {0.f, 0.f, 0.f, 0.f}, acc1 = {0.f, 0.f, 0.f, 0.f};
        acc0 = __builtin_amdgcn_mfma_f32_16x16x32_bf16(a0, bb, acc0, 0, 0, 0);
        acc1 = __builtin_amdgcn_mfma_f32_16x16x32_bf16(a1, bb, acc1, 0, 0, 0);
        int pix = (ty0 + row) * PW + tx0 + n;
        uint2 h0, h1v;
        h0.x = (unsigned)bf16s(acc0[0]) | ((unsigned)bf16s(acc0[1]) << 16);
        h0.y = (unsigned)bf16s(acc0[2]) | ((unsigned)bf16s(acc0[3]) << 16);
        h1v.x = (unsigned)bf16s(acc1[0]) | ((unsigned)bf16s(acc1[1]) << 16);
        h1v.y = (unsigned)bf16s(acc1[2]) | ((unsigned)bf16s(acc1[3]) << 16);
        *(uint2*)&outH[(size_t)pix * 32 + quad * 4] = h0;
        *(uint2*)&outH[(size_t)pix * 32 + 16 + quad * 4] = h1v;
    }
}

// ---------------- fully fused RK stage, 8x8 tile
// regions: x 14x14 (196px, aliased on sH2), h1 12x12 (144px), h2 10x10 (100px)
__global__ __launch_bounds__(256, 4) void fused_stage(
    const float* __restrict__ xin, float* __restrict__ x0,
    float* __restrict__ xacc, float* __restrict__ xst,
    const short* __restrict__ w1p, const short* __restrict__ w2p,
    const short* __restrict__ w3p, const float* __restrict__ b1,
    const float* __restrict__ b2, const float* __restrict__ b3,
    const float* __restrict__ embr, const short* __restrict__ tepsb,
    const float* __restrict__ epsin, float* __restrict__ Sacc,
    float c1, float c2, float dt, int mode) {
    const int tile = blockIdx.x;            // 0..399
    const int b = blockIdx.y;
    const int oy = (tile / 20) * 8, ox = (tile % 20) * 8;
    const int tid = threadIdx.x;
    const int lane = tid & 63, wv = tid >> 6;
    const int n = lane & 15, quad = lane >> 4;

    __shared__ short sH1[144 * 40], sD1[144 * 40];   // 11520 B each
    __shared__ short sH2[100 * 40], sD2[100 * 40];   // 8000 B each
    __shared__ float sBE[32], sB2[32], sB3[4], wsum[4];
    float* sX = (float*)sH2;                         // 588 floats, dead after phase 1

    if (tid < 32) { sBE[tid] = b1[tid] + embr[tid]; sB2[tid] = b2[tid]; }
    if (tid >= 32 && tid < 35) sB3[tid - 32] = b3[tid - 32];

    // ---- stage x region (zero-padded outside image)
    for (int idx = tid; idx < 588; idx += 256) {
        int ci = idx / 196, p = idx - ci * 196;
        int ly = p / 14, lx = p - ly * 14;
        int gy = oy - 3 + ly, gx = ox - 3 + lx;
        float v = 0.0f;
        if ((unsigned)gy < 160u && (unsigned)gx < 160u)
            v = xin[(size_t)(b * 3 + ci) * PSQ + gy * PW + gx];
        sX[idx] = v;
    }
    __syncthreads();

    // ---- phase 1: conv1 over h1 region (144 px, 9 n-tiles)
    {
        int koff[8];
        #pragma unroll
        for (int j = 0; j < 8; ++j) {
            int k = quad * 8 + j;
            int tap = k / 3, ci = k - tap * 3;
            int dy = tap / 3, dx = tap - dy * 3;
            koff[j] = (k < 27) ? (ci * 196 + dy * 14 + dx) : 0;
        }
        short8 a0 = *(const short8*)&w1p[(quad * 32 + n) * 8];
        short8 a1 = *(const short8*)&w1p[(quad * 32 + 16 + n) * 8];
        for (int t = wv; t < 9; t += 4) {
            int p = t * 16 + n;                // < 144
            int ry = p / 12, rx = p - ry * 12;
            int base = ry * 14 + rx;
            float f0 = sX[koff[0] + base], f1 = sX[koff[1] + base];
            float f2 = sX[koff[2] + base], f3 = sX[koff[3] + base];
            float f4 = sX[koff[4] + base], f5 = sX[koff[5] + base];
            float f6 = sX[koff[6] + base], f7 = sX[koff[7] + base];
            unsigned e0 = pk2(f1, f0), e1 = pk2(f3, f2);
            unsigned e2 = pk2(f5, f4), e3 = pk2(f7, f6);
            if (quad == 3) { e1 &= 0x0000FFFFu; e2 = 0u; e3 = 0u; }  // k>=27 pad
            short8 bb = __builtin_bit_cast(short8, (uint4){e0, e1, e2, e3});
            float4v acc0 = {0.f, 0.f, 0.f, 0.f}, acc1 = {0.f, 0.f, 0.f, 0.f};
            acc0 = __builtin_amdgcn_mfma_f32_16x16x32_bf16(a0, bb, acc0, 0, 0, 0);
            acc1 = __builtin_amdgcn_mfma_f32_16x16x32_bf16(a1, bb, acc1, 0, 0, 0);
            int gy = oy - 2 + ry, gx = ox - 2 + rx;
            unsigned im = ((unsigned)gy < 160u && (unsigned)gx < 160u) ? 0xFFFFFFFFu : 0u;
            size_t tbase = im ? ((size_t)(gy * PW + gx) * 32) : 0;
            #pragma unroll
            for (int mt = 0; mt < 2; ++mt) {
                const float4v& ac = mt ? acc1 : acc0;
                int co0 = mt * 16 + quad * 4;
                uint2 t2 = *(const uint2*)&tepsb[tbase + co0];
                float p0 = ac[0] + sBE[co0], p1 = ac[1] + sBE[co0 + 1];
                float p2 = ac[2] + sBE[co0 + 2], p3 = ac[3] + sBE[co0 + 3];
                unsigned hlo = pk2(fmaxf(p1, 0.f), fmaxf(p0, 0.f)) & im;
                unsigned hhi = pk2(fmaxf(p3, 0.f), fmaxf(p2, 0.f)) & im;
                unsigned m0 = ((p0 > 0.f) ? 0x0000FFFFu : 0u) | ((p1 > 0.f) ? 0xFFFF0000u : 0u);
                unsigned m1 = ((p2 > 0.f) ? 0x0000FFFFu : 0u) | ((p3 > 0.f) ? 0xFFFF0000u : 0u);
                *(uint2*)&sH1[p * 40 + co0] = (uint2){hlo, hhi};
                *(uint2*)&sD1[p * 40 + co0] = (uint2){t2.x & m0 & im, t2.y & m1 & im};
            }
        }
    }
    __syncthreads();

    // ---- phase 2: conv2 over h2 region (100 px, 7 n-tiles) — overwrites sX alias
    {
        short8 a2[9][2];
        #pragma unroll
        for (int tap = 0; tap < 9; ++tap) {
            a2[tap][0] = *(const short8*)&w2p[((tap * 4 + quad) * 32 + n) * 8];
            a2[tap][1] = *(const short8*)&w2p[((tap * 4 + quad) * 32 + 16 + n) * 8];
        }
        for (int t = wv; t < 7; t += 4) {
            int p = t * 16 + n;
            int pc = p < 100 ? p : 99;
            int ry = pc / 10, rx = pc - ry * 10;
            int hb = (ry * 12 + rx) * 40 + quad * 8;
            float4v aP0 = {0.f,0.f,0.f,0.f}, aP1 = {0.f,0.f,0.f,0.f};
            float4v aD0 = {0.f,0.f,0.f,0.f}, aD1 = {0.f,0.f,0.f,0.f};
            #pragma unroll
            for (int tap = 0; tap < 9; ++tap) {
                const int dy = tap / 3, dx = tap - dy * 3;
                const int off = (dy * 12 + dx) * 40;
                short8 bp = *(const short8*)&sH1[hb + off];
                short8 bd = *(const short8*)&sD1[hb + off];
                aP0 = __builtin_amdgcn_mfma_f32_16x16x32_bf16(a2[tap][0], bp, aP0, 0, 0, 0);
                aP1 = __builtin_amdgcn_mfma_f32_16x16x32_bf16(a2[tap][1], bp, aP1, 0, 0, 0);
                aD0 = __builtin_amdgcn_mfma_f32_16x16x32_bf16(a2[tap][0], bd, aD0, 0, 0, 0);
                aD1 = __builtin_amdgcn_mfma_f32_16x16x32_bf16(a2[tap][1], bd, aD1, 0, 0, 0);
            }
            if (p < 100) {
                int gy = oy - 1 + ry, gx = ox - 1 + rx;
                unsigned im = ((unsigned)gy < 160u && (unsigned)gx < 160u) ? 0xFFFFFFFFu : 0u;
                #pragma unroll
                for (int mt = 0; mt < 2; ++mt) {
                    const float4v& acP = mt ? aP1 : aP0;
                    const float4v& acD = mt ? aD1 : aD0;
                    int co0 = mt * 16 + quad * 4;
                    float p0 = acP[0] + sB2[co0], p1 = acP[1] + sB2[co0 + 1];
                    float p2 = acP[2] + sB2[co0 + 2], p3 = acP[3] + sB2[co0 + 3];
                    unsigned hlo = pk2(fmaxf(p1, 0.f), fmaxf(p0, 0.f)) & im;
                    unsigned hhi = pk2(fmaxf(p3, 0.f), fmaxf(p2, 0.f)) & im;
                    unsigned m0 = ((p0 > 0.f) ? 0x0000FFFFu : 0u) | ((p1 > 0.f) ? 0xFFFF0000u : 0u);
                    unsigned m1 = ((p2 > 0.f) ? 0x0000FFFFu : 0u) | ((p3 > 0.f) ? 0xFFFF0000u : 0u);
                    unsigned dlo = pk2(acD[1], acD[0]) & m0 & im;
                    unsigned dhi = pk2(acD[3], acD[2]) & m1 & im;
                    *(uint2*)&sH2[p * 40 + co0] = (uint2){hlo, hhi};
                    *(uint2*)&sD2[p * 40 + co0] = (uint2){dlo, dhi};
                }
            }
        }
    }
    __syncthreads();

    // ---- phase 3: conv3 over out tile (64 px, 1 n-tile per wave) + drift + div + RK
    float s = 0.0f;
    {
        short8 a3[9];
        #pragma unroll
        for (int tap = 0; tap < 9; ++tap)
            a3[tap] = *(const short8*)&w3p[((tap * 4 + quad) * 16 + n) * 8];
        int p = wv * 16 + n;                 // 0..63
        int ry = p >> 3, rx = p & 7;
        int hb = (ry * 10 + rx) * 40 + quad * 8;
        float4v aP = {0.f,0.f,0.f,0.f}, aD = {0.f,0.f,0.f,0.f};
        #pragma unroll
        for (int tap = 0; tap < 9; ++tap) {
            const int dy = tap / 3, dx = tap - dy * 3;
            const int off = (dy * 10 + dx) * 40;
            short8 bp = *(const short8*)&sH2[hb + off];
            short8 bd = *(const short8*)&sD2[hb + off];
            aP = __builtin_amdgcn_mfma_f32_16x16x32_bf16(a3[tap], bp, aP, 0, 0, 0);
            aD = __builtin_amdgcn_mfma_f32_16x16x32_bf16(a3[tap], bd, aD, 0, 0, 0);
        }
        if (quad == 0) {
            int gy = oy + ry, gx = ox + rx;
            int pix = gy * PW + gx;
            #pragma unroll
            for (int c = 0; c < 3; ++c) {
                float y = aP[c] + sB3[c];
                size_t gi = (size_t)(b * 3 + c) * PSQ + pix;
                float xv = xin[gi];           // L1/L2-hot (staged earlier)
                float k = -c1 * xv - c2 * y;
                if (mode == 0) {
                    xacc[gi] = k;
                    xst[gi] = xv + 0.5f * dt * k;    // xin == x0 at stage 0
                } else if (mode == 1) {
                    xacc[gi] += 2.0f * k;
                    xst[gi] = x0[gi] + 0.5f * dt * k;
                } else if (mode == 2) {
                    xacc[gi] += 2.0f * k;
                    xst[gi] = x0[gi] + dt * k;
                } else {
                    x0[gi] += (dt / 6.0f) * (xacc[gi] + k);
                }
                s += aD[c] * epsin[c * PSQ + pix];
            }
        }
    }
    #pragma unroll
    for (int off = 32; off > 0; off >>= 1) s += __shfl_down(s, off);
    if (lane == 0) wsum[wv] = s;
    __syncthreads();
    if (tid == 0) atomicAdd(&Sacc[b], wsum[0] + wsum[1] + wsum[2] + wsum[3]);
}

// ---------------- sum z^2 per batch (parallel over 25 segments)
__global__ void sumz2_kernel(const float* __restrict__ x0, float* __restrict__ sumz2) {
    int b = blockIdx.x, seg = blockIdx.y, tid = threadIdx.x;
    const float* p = x0 + (size_t)b * NDIM + seg * 3072;
    float s = 0.0f;
    for (int i = tid; i < 3072; i += 256) { float v = p[i]; s += v * v; }
    #pragma unroll
    for (int off = 32; off > 0; off >>= 1) s += __shfl_down(s, off);
    __shared__ float wsum[4];
    if ((tid & 63) == 0) wsum[tid >> 6] = s;
    __syncthreads();
    if (tid == 0) atomicAdd(&sumz2[b], wsum[0] + wsum[1] + wsum[2] + wsum[3]);
}

// ---------------- final bpd
__global__ void bpd_kernel(const float* __restrict__ S, const float* __restrict__ sumz2,
                           float* __restrict__ out, MC40 mc) {
    int b = threadIdx.x;
    if (b >= NB) return;
    float lp = mc.A;
    for (int r = 0; r < 40; r++) lp -= mc.m[r] * S[r * 4 + b];
    float prior = -70574.479354f - 0.5f * sumz2[b];
    out[b] = -(prior + lp) * 1.8785164100960743e-5f;
}

extern "C" void kernel_launch(void* const* d_in, const int* in_sizes, int n_in,
                              void* d_out, int out_size, void* d_ws, size_t ws_size,
                              hipStream_t stream) {
    const float* patches = (const float*)d_in[0];
    const float* epsin = (const float*)d_in[1];
    const float* w1 = (const float*)d_in[2];
    const float* b1 = (const float*)d_in[3];
    const float* wt = (const float*)d_in[4];
    const float* bt = (const float*)d_in[5];
    const float* w2 = (const float*)d_in[6];
    const float* b2 = (const float*)d_in[7];
    const float* w3 = (const float*)d_in[8];
    const float* b3 = (const float*)d_in[9];
    float* outp = (float*)d_out;
    char* wsb = (char*)d_ws;

    float* Sbuf  = (float*)(wsb + 0);          // 160 f
    float* sumz2 = (float*)(wsb + 640);        // 4 f
    float* emb   = (float*)(wsb + 1024);       // 1280 f
    short* w1p   = (short*)(wsb + 6144);       // 1024 bf16
    short* w2p   = (short*)(wsb + 8192);       // 9216 bf16
    short* w3p   = (short*)(wsb + 26624);      // 4608 bf16
    short* tepsb = (short*)(wsb + 36864);      // 819200 bf16
    float* x0    = (float*)(wsb + 1675264);    // NX f
    float* xacc  = (float*)(wsb + 2904064);
    float* xst   = (float*)(wsb + 4132864);    // end ~5.4 MB

    const double dt = (1.0 - 1e-5) / 10.0;
    TS40 ts; MC40 mc;
    float c1a[40], c2a[40];
    double A = 0.0;
    const double wgt[4] = {1.0, 2.0, 2.0, 1.0};
    for (int i = 0; i < 10; i++) {
        double t0 = 1e-5 + dt * i;
        double tr[4] = {t0, t0 + 0.5 * dt, t0 + 0.5 * dt, t0 + dt};
        for (int s = 0; s < 4; s++) {
            int r = i * 4 + s;
            double t = tr[s];
            double beta = 0.1 + 19.9 * t;
            double lmc = -0.25 * t * t * 19.9 - 0.05 * t;
            double stdv = 1.0 - exp(2.0 * lmc);
            double g2 = beta * (1.0 - exp(4.0 * lmc));
            double c2 = 0.5 * g2 / stdv;
            ts.t[r] = (float)t;
            c1a[r] = (float)(0.5 * beta);
            c2a[r] = (float)c2;
            double coef = dt / 6.0 * wgt[s];
            mc.m[r] = (float)(coef * c2);
            A += coef * (-0.5 * beta * (double)NDIM);
        }
    }
    mc.A = (float)A;

    hipMemsetAsync(wsb, 0, 656, stream);  // Sbuf + sumz2
    hipMemcpyAsync(x0, patches, NX * sizeof(float), hipMemcpyDeviceToDevice, stream);

    emb_kernel<<<40, 64, 0, stream>>>(wt, bt, emb, ts);
    repack_kernel<<<36, 256, 0, stream>>>(w1, w2, w3, w1p, w2p, w3p);
    teps_conv1<<<100, 256, 0, stream>>>(epsin, w1p, tepsb);

    for (int i = 0; i < 10; i++) {
        for (int s = 0; s < 4; s++) {
            int r = i * 4 + s;
            const float* xin = (s == 0) ? x0 : xst;
            fused_stage<<<dim3(400, NB), 256, 0, stream>>>(
                xin, x0, xacc, xst, w1p, w2p, w3p, b1, b2, b3,
                emb + r * 32, tepsb, epsin, Sbuf + r * 4,
                c1a[r], c2a[r], (float)dt, s);
        }
    }
    sumz2_kernel<<<dim3(NB, 25), 256, 0, stream>>>(x0, sumz2);
    bpd_kernel<<<1, 64, 0, stream>>>(Sbuf, sumz2, outp, mc);
}